// Round 1
// 1714.165 us; speedup vs baseline: 1.1968x; 1.1968x over previous
//
#include <hip/hip_runtime.h>
#include <cstddef>

// BasicRNN, Round 4.
// Phase A (parallel): X = obs @ W_in^T + b_in + b_h  -> hs region of d_out
// Phase B (persistent): recurrence, 16 teams x 8 wgs x 512 threads (128 blocks).
//   wg owns 128 rows of W_h as REGISTER-resident bf16 MFMA fragments
//   (32 frags/lane, 16 rows/wave x 8 waves). team owns 4 batch rows.
//   Exchange: self-tagged 8B words [3 bf16 | step tag] through relaxed
//   agent-scope atomics, 2-slab ping-pong, NO flags, NO fences, NO drains.
//   vs round 3: half the blocks (poll LLC traffic -57%), skip-self polling
//   (own block injected from registers), fragment-major LDS A-layout
//   (conflict-free ds_read_b128, 4-lane broadcast).
// Phase C (parallel): outs = hs @ W_out^T + b_out

static constexpr int Bb = 64;
static constexpr int Tt = 512;
static constexpr int Dd = 256;
static constexpr int Hh = 1024;
static constexpr int Oo = 256;

typedef __attribute__((ext_vector_type(8))) short bf16x8;
typedef __attribute__((ext_vector_type(4))) float f32x4;
typedef unsigned long long ull;

static __device__ __forceinline__ unsigned short f2b(float f) {
    unsigned int u = __float_as_uint(f);
    u = (u + 0x7fffu + ((u >> 16) & 1u)) >> 16;
    return (unsigned short)u;
}
static __device__ __forceinline__ ull pack4(float a, float b, float c, float d) {
    return (ull)f2b(a) | ((ull)f2b(b) << 16) | ((ull)f2b(c) << 32) | ((ull)f2b(d) << 48);
}

// Fragment-major LDS address for h value (row r in 0..1023, batch m in 0..3):
// layout [k-chunk s = r>>5][m][octet = (r>>3)&3][j = r&7], shorts.
// MFMA A-read: lane l reads 8 shorts at s*128 + (l&3)*32 + (l>>4)*8
//   -> A[m=l&15][k=(l>>4)*8+j] with batch = m&3 (4-lane same-address broadcast,
//      2-way max bank aliasing on b128 = free).
static __device__ __forceinline__ int hla_addr(int r, int m) {
    return ((r >> 5) << 7) + (m << 5) + (((r >> 3) & 3) << 3) + (r & 7);
}

// ---------------------------------------------------------------- fp32 GEMM
// (unchanged from rounds 1-3 — known good)
__global__ __launch_bounds__(256) void gemm_bt_kernel(const float* __restrict__ A,
                                                      const float* __restrict__ Bt,
                                                      const float* __restrict__ bias1,
                                                      const float* __restrict__ bias2,
                                                      float* __restrict__ C,
                                                      int M, int N, int K)
{
    __shared__ float As[128 * 17];
    __shared__ float Bs[128 * 17];
    const int tid = threadIdx.x;
    const int nTiles = N >> 7;
    const int mt = blockIdx.x / nTiles;
    const int nt = blockIdx.x - mt * nTiles;
    const int m0 = mt << 7, n0 = nt << 7;
    const int tx = tid & 15, ty = tid >> 4;

    const int row = tid >> 1;
    const int c8  = (tid & 1) << 3;

    float acc[8][8] = {};

    for (int kt = 0; kt < K; kt += 16) {
        const float4 a0 = *(const float4*)&A [(size_t)(m0 + row) * K + kt + c8];
        const float4 a1 = *(const float4*)&A [(size_t)(m0 + row) * K + kt + c8 + 4];
        const float4 b0 = *(const float4*)&Bt[(size_t)(n0 + row) * K + kt + c8];
        const float4 b1 = *(const float4*)&Bt[(size_t)(n0 + row) * K + kt + c8 + 4];
        __syncthreads();
        {
            const int ab = row * 17 + c8;
            As[ab + 0] = a0.x; As[ab + 1] = a0.y; As[ab + 2] = a0.z; As[ab + 3] = a0.w;
            As[ab + 4] = a1.x; As[ab + 5] = a1.y; As[ab + 6] = a1.z; As[ab + 7] = a1.w;
            Bs[ab + 0] = b0.x; Bs[ab + 1] = b0.y; Bs[ab + 2] = b0.z; Bs[ab + 3] = b0.w;
            Bs[ab + 4] = b1.x; Bs[ab + 5] = b1.y; Bs[ab + 6] = b1.z; Bs[ab + 7] = b1.w;
        }
        __syncthreads();
#pragma unroll
        for (int kk = 0; kk < 16; ++kk) {
            float af[8], bf[8];
#pragma unroll
            for (int i = 0; i < 8; ++i) af[i] = As[(ty * 8 + i) * 17 + kk];
#pragma unroll
            for (int j = 0; j < 4; ++j) bf[j] = Bs[(tx * 4 + j) * 17 + kk];
#pragma unroll
            for (int j = 0; j < 4; ++j) bf[4 + j] = Bs[(64 + tx * 4 + j) * 17 + kk];
#pragma unroll
            for (int i = 0; i < 8; ++i) {
#pragma unroll
                for (int j = 0; j < 8; ++j) {
                    acc[i][j] = fmaf(af[i], bf[j], acc[i][j]);
                }
            }
        }
    }

    float bs[8];
#pragma unroll
    for (int j = 0; j < 4; ++j) {
        const int n1 = n0 + tx * 4 + j;
        const int n2 = n0 + 64 + tx * 4 + j;
        bs[j]     = bias1[n1] + (bias2 ? bias2[n1] : 0.0f);
        bs[4 + j] = bias1[n2] + (bias2 ? bias2[n2] : 0.0f);
    }
#pragma unroll
    for (int i = 0; i < 8; ++i) {
        const int m = m0 + ty * 8 + i;
        float4 v0 = make_float4(acc[i][0] + bs[0], acc[i][1] + bs[1],
                                acc[i][2] + bs[2], acc[i][3] + bs[3]);
        float4 v1 = make_float4(acc[i][4] + bs[4], acc[i][5] + bs[5],
                                acc[i][6] + bs[6], acc[i][7] + bs[7]);
        *(float4*)&C[(size_t)m * N + n0 + tx * 4]      = v0;
        *(float4*)&C[(size_t)m * N + n0 + 64 + tx * 4] = v1;
    }
}

// ---------------------------------------------------------------- recurrence
// 128 blocks x 512 threads. team = bid&15, wg = bid>>4 (0..7). wg owns 128
// W_h rows (wave wv: rows r0+wv*16..+15). LDS ~9.2 KB, VGPR <=256 (bounds)
// -> all 128 blocks trivially co-resident on 256 CUs -> polling deadlock-free.
//
// MFMA 16x16x32 bf16 layout (HW-verified): A: lane l = A[m=l&15][k=(l>>4)*8+j];
// B: lane l = B[k=(l>>4)*8+j][n=l&15]; D: lane l reg i = D[m=(l>>4)*4+i][n=l&15].
// A[m][k] = h[batch m&3][k] (batch rows replicated over m); B[k][n] = W[row][k]
// for row = r0 + wv*16 + n. Valid outputs at m=0..3 -> lanes 0..15, regs 0..3.
//
// Exchange word w of wg j covers flat shorts f=3w..3w+2 of that wg's
// [4 batch][128 row] bf16 block; tag in bits 48..63 = step index of the h it
// carries. Slab: ull hx[2][16 team][8 wg][176] (171 used). Readers poll only
// the 7 REMOTE wgs (1197 words, 2-3/thread); own block is written from regs.
__global__ __launch_bounds__(512, 2) void rnn_kernel(float* __restrict__ Xhs, // [64][512][1024]
                                                     const float* __restrict__ h0,
                                                     const float* __restrict__ Wh,
                                                     ull* __restrict__ hx)
{
    __shared__ short hlA[32 * 128];  // fragment-major team h, bf16 (8 KB)
    __shared__ short hxl[520];       // publish staging [4][128], 512 used

    const int tid  = threadIdx.x;
    const int bid  = blockIdx.x;
    const int team = bid & 15;
    const int wg   = bid >> 4;       // 0..7
    const int r0   = wg << 7;        // 128 W_h rows
    const int b0   = team << 2;      // 4 batch rows

    const int lane = tid & 63;
    const int wv   = tid >> 6;       // 0..7

    // ---- one-time: 128-row W slice -> register-resident bf16 B-fragments
    bf16x8 wfrag[32];
    {
        const float* wrow = Wh + (size_t)(r0 + wv * 16 + (lane & 15)) * Hh + ((lane >> 4) << 3);
#pragma unroll
        for (int s = 0; s < 32; ++s) {
            const float4 lo = *(const float4*)(wrow + s * 32);
            const float4 hi = *(const float4*)(wrow + s * 32 + 4);
            bf16x8 w;
            w[0] = (short)f2b(lo.x); w[1] = (short)f2b(lo.y);
            w[2] = (short)f2b(lo.z); w[3] = (short)f2b(lo.w);
            w[4] = (short)f2b(hi.x); w[5] = (short)f2b(hi.y);
            w[6] = (short)f2b(hi.z); w[7] = (short)f2b(hi.w);
            wfrag[s] = w;
        }
    }

    // ---- one-time: h0 -> hlA (bf16, fragment-major)
#pragma unroll
    for (int it = 0; it < 2; ++it) {
        const int idx = it * 512 + tid;   // 1024 float4 chunks of [4][1024]
        const int b   = idx >> 8;
        const int k0  = (idx & 255) << 2;
        const float4 v = *(const float4*)&h0[(size_t)(b0 + b) * Hh + k0];
        *(ull*)&hlA[hla_addr(k0, b)] = pack4(v.x, v.y, v.z, v.w);
    }

    // ---- per-thread word assignment (7 remote wgs x 171 words = 1197)
    const int nw = (tid < 173) ? 3 : 2;
    int soff[3], fb3[3], cb3[3];
#pragma unroll
    for (int j = 0; j < 3; ++j) {
        int q = tid + j * 512; if (q >= 1197) q = 0;  // dummy, never polled
        const int wr = q / 171;
        const int w  = q - 171 * wr;
        const int wi = wr + (wr >= wg ? 1 : 0);       // skip self
        soff[j] = wi * 176 + w;
        fb3[j]  = 3 * w;
        cb3[j]  = wi << 7;
    }

    // ---- extraction-lane state: lane<16 owns (batch i=0..3, row exrow)
    const bool ex    = (lane < 16);
    const int  exrow = r0 + wv * 16 + lane;
    float hprev[4] = {0.f, 0.f, 0.f, 0.f};
    float xr[4]    = {0.f, 0.f, 0.f, 0.f};
    float xn[4]    = {0.f, 0.f, 0.f, 0.f};
    if (ex) {
#pragma unroll
        for (int i = 0; i < 4; ++i) {
            hprev[i] = h0[(size_t)(b0 + i) * Hh + exrow];
            xr[i]    = Xhs[(size_t)(b0 + i) * Tt * Hh + exrow];   // x(0)
        }
    }
    __syncthreads();

    const int aoff = (lane & 3) * 32 + ((lane >> 4) << 3);   // shorts

    for (int t = 0; t < Tt; ++t) {
        // ---- pre = h(t) @ W^T : 32 MFMAs in 4 independent chains
        f32x4 acc0 = {0.f, 0.f, 0.f, 0.f}, acc1 = acc0, acc2 = acc0, acc3 = acc0;
#pragma unroll
        for (int s = 0; s < 32; s += 4) {
            acc0 = __builtin_amdgcn_mfma_f32_16x16x32_bf16(
                       *(const bf16x8*)(hlA + (s + 0) * 128 + aoff), wfrag[s + 0], acc0, 0, 0, 0);
            acc1 = __builtin_amdgcn_mfma_f32_16x16x32_bf16(
                       *(const bf16x8*)(hlA + (s + 1) * 128 + aoff), wfrag[s + 1], acc1, 0, 0, 0);
            acc2 = __builtin_amdgcn_mfma_f32_16x16x32_bf16(
                       *(const bf16x8*)(hlA + (s + 2) * 128 + aoff), wfrag[s + 2], acc2, 0, 0, 0);
            acc3 = __builtin_amdgcn_mfma_f32_16x16x32_bf16(
                       *(const bf16x8*)(hlA + (s + 3) * 128 + aoff), wfrag[s + 3], acc3, 0, 0, 0);
        }
        const f32x4 accs01 = acc0 + acc1;
        const f32x4 accs23 = acc2 + acc3;
        const f32x4 acc    = accs01 + accs23;

        // ---- extract h(t+1) for owned (batch, row), stage bf16 publish block
        float hnew[4] = {0.f, 0.f, 0.f, 0.f};
        unsigned short hb[4] = {0, 0, 0, 0};
        if (ex) {
#pragma unroll
            for (int i = 0; i < 4; ++i) {
                const float pre = acc[i] + xr[i];
                hnew[i]  = 0.5f * fmaxf(pre, 0.0f) + 0.5f * hprev[i];
                hprev[i] = hnew[i];
                hb[i]    = f2b(hnew[i]);
                hxl[i * 128 + wv * 16 + lane] = (short)hb[i];
            }
        }
        __syncthreads();

        if (t + 1 < Tt) {
            ull* __restrict__ slab = hx + ((size_t)(((t + 1) & 1) * 16 + team)) * (8 * 176);

            // ---- publish FIRST (critical path): 171 self-tagged words
            if (tid < 171) {
                const int f0 = 3 * tid;
                const ull w = (ull)(unsigned short)hxl[f0]
                            | ((ull)(unsigned short)hxl[f0 + 1] << 16)
                            | ((ull)(unsigned short)hxl[f0 + 2] << 32)
                            | ((ull)(unsigned int)(t + 1) << 48);
                __hip_atomic_store(&slab[wg * 176 + tid], w,
                                   __ATOMIC_RELAXED, __HIP_MEMORY_SCOPE_AGENT);
            }
            // ---- off critical path: self h -> hlA (from regs), hs store,
            //      next-x prefetch
            if (ex) {
#pragma unroll
                for (int i = 0; i < 4; ++i)
                    hlA[hla_addr(exrow, i)] = (short)hb[i];
#pragma unroll
                for (int i = 0; i < 4; ++i)
                    Xhs[((size_t)(b0 + i) * Tt + t) * Hh + exrow] = hnew[i];
#pragma unroll
                for (int i = 0; i < 4; ++i)
                    xn[i] = Xhs[((size_t)(b0 + i) * Tt + (t + 1)) * Hh + exrow];
            }

            // ---- poll remote wgs' h(t+1) words; observing load IS the payload
            const unsigned short want = (unsigned short)(t + 1);
            ull  pw[3];
            bool dn[3] = {false, false, false};
            int  rem = nw;
            while (rem > 0) {
#pragma unroll
                for (int j = 0; j < 3; ++j) {
                    if (j < nw && !dn[j]) {
                        pw[j] = __hip_atomic_load(&slab[soff[j]],
                                                  __ATOMIC_RELAXED, __HIP_MEMORY_SCOPE_AGENT);
                    }
                }
#pragma unroll
                for (int j = 0; j < 3; ++j) {
                    if (j < nw && !dn[j] && (unsigned short)(pw[j] >> 48) == want) {
                        dn[j] = true; --rem;
                        const int f0 = fb3[j], cb = cb3[j];
                        const unsigned short s0 = (unsigned short)pw[j];
                        const unsigned short s1 = (unsigned short)(pw[j] >> 16);
                        const unsigned short s2 = (unsigned short)(pw[j] >> 32);
                        // flat f of [4 batch][128 row]: m = f>>7, row = cb + (f&127)
                        hlA[hla_addr(cb + (f0 & 127), f0 >> 7)]             = (short)s0;
                        hlA[hla_addr(cb + ((f0 + 1) & 127), (f0 + 1) >> 7)] = (short)s1;
                        if (f0 + 2 < 512)
                            hlA[hla_addr(cb + ((f0 + 2) & 127), (f0 + 2) >> 7)] = (short)s2;
                    }
                }
            }
            if (ex) {
#pragma unroll
                for (int i = 0; i < 4; ++i) xr[i] = xn[i];
            }
            __syncthreads();   // hlA now holds h(t+1)
        } else {
            // last step: just emit hs
            if (ex) {
#pragma unroll
                for (int i = 0; i < 4; ++i)
                    Xhs[((size_t)(b0 + i) * Tt + t) * Hh + exrow] = hnew[i];
            }
        }
    }
}

// ---------------------------------------------------------------- launch
extern "C" void kernel_launch(void* const* d_in, const int* in_sizes, int n_in,
                              void* d_out, int out_size, void* d_ws, size_t ws_size,
                              hipStream_t stream)
{
    (void)in_sizes; (void)n_in; (void)out_size; (void)ws_size;

    const float* obs  = (const float*)d_in[0];  // [64][512][256]
    const float* h0   = (const float*)d_in[1];  // [64][1024]
    const float* Win  = (const float*)d_in[2];  // [1024][256]
    const float* bin  = (const float*)d_in[3];  // [1024]
    const float* Wh   = (const float*)d_in[4];  // [1024][1024]
    const float* bh   = (const float*)d_in[5];  // [1024]
    const float* Wout = (const float*)d_in[6];  // [256][1024]
    const float* bout = (const float*)d_in[7];  // [256]

    float* outs = (float*)d_out;                   // [64][512][256]
    float* hs   = outs + (size_t)Bb * Tt * Oo;     // [64][512][1024] (doubles as X)

    ull* hx = (ull*)d_ws;                          // [2][16][8][176] = 360448 B

    // Phase A: X = obs @ W_in^T + b_in + b_h  -> hs region
    gemm_bt_kernel<<<(Bb * Tt / 128) * (Hh / 128), 256, 0, stream>>>(
        obs, Win, bin, bh, hs, Bb * Tt, Hh, Dd);

    // Phase B: sequential recurrence (in-place X -> hs). Tags ping-pong over
    // 2 slabs; 0xAA ws poison reads as tag 0xAAAA which matches no step.
    rnn_kernel<<<128, 512, 0, stream>>>(hs, h0, Wh, hx);

    // Phase C: outs = hs @ W_out^T + b_out
    gemm_bt_kernel<<<(Bb * Tt / 128) * (Oo / 128), 256, 0, stream>>>(
        hs, Wout, bout, nullptr, outs, Bb * Tt, Oo, Hh);
}

// Round 3
// 1680.458 us; speedup vs baseline: 1.2208x; 1.0201x over previous
//
#include <hip/hip_runtime.h>
#include <cstddef>

// BasicRNN, Round 6.
// Phase A (parallel): X = obs @ W_in^T + b_in + b_h  -> hs region of d_out
// Phase B (persistent): recurrence, 16 teams x 8 wgs x 512 threads (128 blocks).
//   wg owns 128 rows of W_h register-resident (32 bf16x8 frags/lane).
//   team owns 4 batch rows.
//   R5 structure kept: hlA double-buffered -> ONE barrier/step (no hxl
//   staging), publish straight from ex-thread registers, x(t) load hoisted
//   above MFMA, hs store after poll.
//   R4 exchange primitive restored: 8B self-tagged words via __hip_atomic_
//   store/load (RELAXED, AGENT scope) — 8B single-copy atomicity and
//   compiler-emitted cache-scope bits (R5's hand-rolled 16B sc0/sc1 asm had
//   unverified tearing/coherence semantics -> failed).
//   Word pair per row r: [hb0 hb1 hb2|tag16][hb3|tag16], 256 words/wg.
// Phase C (parallel): outs = hs @ W_out^T + b_out

static constexpr int Bb = 64;
static constexpr int Tt = 512;
static constexpr int Dd = 256;
static constexpr int Hh = 1024;
static constexpr int Oo = 256;

typedef __attribute__((ext_vector_type(8))) short bf16x8;
typedef __attribute__((ext_vector_type(4))) float f32x4;
typedef unsigned long long ull;

static __device__ __forceinline__ unsigned short f2b(float f) {
    unsigned int u = __float_as_uint(f);
    u = (u + 0x7fffu + ((u >> 16) & 1u)) >> 16;
    return (unsigned short)u;
}
static __device__ __forceinline__ ull pack4(float a, float b, float c, float d) {
    return (ull)f2b(a) | ((ull)f2b(b) << 16) | ((ull)f2b(c) << 32) | ((ull)f2b(d) << 48);
}

// Fragment-major LDS layout for h (row r 0..1023, batch m 0..3):
// [k-chunk r>>5][m][octet (r>>3)&3][j r&7], shorts. MFMA A-read: lane l reads
// 8 shorts at s*128 + (l&3)*32 + (l>>4)*8 -> 4-lane broadcast, 2-way max = free.
static __device__ __forceinline__ int hla_base(int r) {
    return ((r >> 5) << 7) + (((r >> 3) & 3) << 3) + (r & 7);
}
static __device__ __forceinline__ int hla_addr(int r, int m) {
    return hla_base(r) + (m << 5);
}

// ---------------------------------------------------------------- fp32 GEMM
// (unchanged from rounds 1-5 — known good)
__global__ __launch_bounds__(256) void gemm_bt_kernel(const float* __restrict__ A,
                                                      const float* __restrict__ Bt,
                                                      const float* __restrict__ bias1,
                                                      const float* __restrict__ bias2,
                                                      float* __restrict__ C,
                                                      int M, int N, int K)
{
    __shared__ float As[128 * 17];
    __shared__ float Bs[128 * 17];
    const int tid = threadIdx.x;
    const int nTiles = N >> 7;
    const int mt = blockIdx.x / nTiles;
    const int nt = blockIdx.x - mt * nTiles;
    const int m0 = mt << 7, n0 = nt << 7;
    const int tx = tid & 15, ty = tid >> 4;

    const int row = tid >> 1;
    const int c8  = (tid & 1) << 3;

    float acc[8][8] = {};

    for (int kt = 0; kt < K; kt += 16) {
        const float4 a0 = *(const float4*)&A [(size_t)(m0 + row) * K + kt + c8];
        const float4 a1 = *(const float4*)&A [(size_t)(m0 + row) * K + kt + c8 + 4];
        const float4 b0 = *(const float4*)&Bt[(size_t)(n0 + row) * K + kt + c8];
        const float4 b1 = *(const float4*)&Bt[(size_t)(n0 + row) * K + kt + c8 + 4];
        __syncthreads();
        {
            const int ab = row * 17 + c8;
            As[ab + 0] = a0.x; As[ab + 1] = a0.y; As[ab + 2] = a0.z; As[ab + 3] = a0.w;
            As[ab + 4] = a1.x; As[ab + 5] = a1.y; As[ab + 6] = a1.z; As[ab + 7] = a1.w;
            Bs[ab + 0] = b0.x; Bs[ab + 1] = b0.y; Bs[ab + 2] = b0.z; Bs[ab + 3] = b0.w;
            Bs[ab + 4] = b1.x; Bs[ab + 5] = b1.y; Bs[ab + 6] = b1.z; Bs[ab + 7] = b1.w;
        }
        __syncthreads();
#pragma unroll
        for (int kk = 0; kk < 16; ++kk) {
            float af[8], bf[8];
#pragma unroll
            for (int i = 0; i < 8; ++i) af[i] = As[(ty * 8 + i) * 17 + kk];
#pragma unroll
            for (int j = 0; j < 4; ++j) bf[j] = Bs[(tx * 4 + j) * 17 + kk];
#pragma unroll
            for (int j = 0; j < 4; ++j) bf[4 + j] = Bs[(64 + tx * 4 + j) * 17 + kk];
#pragma unroll
            for (int i = 0; i < 8; ++i) {
#pragma unroll
                for (int j = 0; j < 8; ++j) {
                    acc[i][j] = fmaf(af[i], bf[j], acc[i][j]);
                }
            }
        }
    }

    float bs[8];
#pragma unroll
    for (int j = 0; j < 4; ++j) {
        const int n1 = n0 + tx * 4 + j;
        const int n2 = n0 + 64 + tx * 4 + j;
        bs[j]     = bias1[n1] + (bias2 ? bias2[n1] : 0.0f);
        bs[4 + j] = bias1[n2] + (bias2 ? bias2[n2] : 0.0f);
    }
#pragma unroll
    for (int i = 0; i < 8; ++i) {
        const int m = m0 + ty * 8 + i;
        float4 v0 = make_float4(acc[i][0] + bs[0], acc[i][1] + bs[1],
                                acc[i][2] + bs[2], acc[i][3] + bs[3]);
        float4 v1 = make_float4(acc[i][4] + bs[4], acc[i][5] + bs[5],
                                acc[i][6] + bs[6], acc[i][7] + bs[7]);
        *(float4*)&C[(size_t)m * N + n0 + tx * 4]      = v0;
        *(float4*)&C[(size_t)m * N + n0 + 64 + tx * 4] = v1;
    }
}

// ---------------------------------------------------------------- recurrence
// 128 blocks x 512 threads. team = bid&15, wg = bid>>4 (0..7), 128 W_h rows/wg.
// ~16.5 KB LDS, <=256 unified regs -> >=1 block/CU, 128 blocks co-resident ->
// polling deadlock-free.
//
// MFMA 16x16x32 bf16 (HW-verified): A: lane l = A[m=l&15][k=(l>>4)*8+j];
// D: lane l reg i = D[m=(l>>4)*4+i][n=l&15]. Batch replicated over m&3;
// valid outputs at lanes 0..15 regs 0..3.
//
// Exchange: word pair for row r of wg j at slab[j*256 + 2*(r-128j) + {0,1}]:
// lo = [hb0 hb1 hb2 | tag16], hi = [hb3 | tag16]; tag = step index of the h
// it carries. Slab: ull hx[2][16 team][8 wg][256] = 512 KB of d_ws.
// A wg leads its team by at most 1 step, so 2 slabs suffice. Every slot is
// rewritten every 2 steps; 0xAA ws poison -> tag 0xAAAA matches no step.
__global__ __launch_bounds__(512, 2) void rnn_kernel(float* __restrict__ Xhs, // [64][512][1024]
                                                     const float* __restrict__ h0,
                                                     const float* __restrict__ Wh,
                                                     ull* __restrict__ hx)
{
    __shared__ short hlA[2][32 * 128];   // double-buffered fragment-major h (16 KB)

    const int tid  = threadIdx.x;
    const int bid  = blockIdx.x;
    const int team = bid & 15;
    const int wg   = bid >> 4;       // 0..7
    const int r0   = wg << 7;        // 128 W_h rows
    const int b0   = team << 2;      // 4 batch rows

    const int lane = tid & 63;
    const int wv   = tid >> 6;       // 0..7

    // ---- one-time: 128-row W slice -> register-resident bf16 B-fragments
    bf16x8 wfrag[32];
    {
        const float* wrow = Wh + (size_t)(r0 + wv * 16 + (lane & 15)) * Hh + ((lane >> 4) << 3);
#pragma unroll
        for (int s = 0; s < 32; ++s) {
            const float4 lo = *(const float4*)(wrow + s * 32);
            const float4 hi = *(const float4*)(wrow + s * 32 + 4);
            bf16x8 w;
            w[0] = (short)f2b(lo.x); w[1] = (short)f2b(lo.y);
            w[2] = (short)f2b(lo.z); w[3] = (short)f2b(lo.w);
            w[4] = (short)f2b(hi.x); w[5] = (short)f2b(hi.y);
            w[6] = (short)f2b(hi.z); w[7] = (short)f2b(hi.w);
            wfrag[s] = w;
        }
    }

    // ---- one-time: h0 -> hlA[0] (bf16, fragment-major)
#pragma unroll
    for (int it = 0; it < 2; ++it) {
        const int idx = it * 512 + tid;   // 1024 float4 chunks of [4][1024]
        const int b   = idx >> 8;
        const int k0  = (idx & 255) << 2;
        const float4 v = *(const float4*)&h0[(size_t)(b0 + b) * Hh + k0];
        *(ull*)&hlA[0][hla_addr(k0, b)] = pack4(v.x, v.y, v.z, v.w);
    }

    // ---- per-thread poll assignment: row-pairs (7 remote wgs x 128 = 896)
    // pair q: remote ordinal wr = q>>7, local row rl = q&127.
    const int npair = (tid < 384) ? 2 : 1;
    int soff[2], sbase[2];
#pragma unroll
    for (int j = 0; j < 2; ++j) {
        int q = tid + j * 512; if (q >= 896) q = 0;   // dummy, never polled
        const int wr = q >> 7;
        const int rl = q & 127;
        const int wi = wr + ((wr >= wg) ? 1 : 0);      // skip self
        soff[j]  = (wi << 8) + (rl << 1);
        sbase[j] = hla_base((wi << 7) + rl);
    }

    // ---- extraction-lane state: lane<16 owns (batch i=0..3, row exrow)
    const bool ex    = (lane < 16);
    const int  exrow = r0 + wv * 16 + lane;
    const int  sb    = hla_base(exrow);
    float hprev[4] = {0.f, 0.f, 0.f, 0.f};
    if (ex) {
#pragma unroll
        for (int i = 0; i < 4; ++i)
            hprev[i] = h0[(size_t)(b0 + i) * Hh + exrow];
    }
    __syncthreads();

    const int aoff = (lane & 3) * 32 + ((lane >> 4) << 3);   // shorts

    for (int t = 0; t < Tt; ++t) {
        const short* hc = hlA[t & 1];
        short*       hn = hlA[(t + 1) & 1];

        // ---- x(t) load issued first: hides under the MFMA block
        float xr[4] = {0.f, 0.f, 0.f, 0.f};
        if (ex) {
#pragma unroll
            for (int i = 0; i < 4; ++i)
                xr[i] = Xhs[((size_t)(b0 + i) * Tt + t) * Hh + exrow];
        }

        // ---- pre = h(t) @ W^T : 32 MFMAs in 4 independent chains
        f32x4 acc0 = {0.f, 0.f, 0.f, 0.f}, acc1 = acc0, acc2 = acc0, acc3 = acc0;
#pragma unroll
        for (int s = 0; s < 32; s += 4) {
            acc0 = __builtin_amdgcn_mfma_f32_16x16x32_bf16(
                       *(const bf16x8*)(hc + (s + 0) * 128 + aoff), wfrag[s + 0], acc0, 0, 0, 0);
            acc1 = __builtin_amdgcn_mfma_f32_16x16x32_bf16(
                       *(const bf16x8*)(hc + (s + 1) * 128 + aoff), wfrag[s + 1], acc1, 0, 0, 0);
            acc2 = __builtin_amdgcn_mfma_f32_16x16x32_bf16(
                       *(const bf16x8*)(hc + (s + 2) * 128 + aoff), wfrag[s + 2], acc2, 0, 0, 0);
            acc3 = __builtin_amdgcn_mfma_f32_16x16x32_bf16(
                       *(const bf16x8*)(hc + (s + 3) * 128 + aoff), wfrag[s + 3], acc3, 0, 0, 0);
        }
        const f32x4 accs01 = acc0 + acc1;
        const f32x4 accs23 = acc2 + acc3;
        const f32x4 acc    = accs01 + accs23;

        // ---- extract h(t+1) for owned (batch, row)
        float hnew[4] = {0.f, 0.f, 0.f, 0.f};
        unsigned short hb[4] = {0, 0, 0, 0};
        if (ex) {
#pragma unroll
            for (int i = 0; i < 4; ++i) {
                const float pre = acc[i] + xr[i];
                hnew[i]  = 0.5f * fmaxf(pre, 0.0f) + 0.5f * hprev[i];
                hprev[i] = hnew[i];
                hb[i]    = f2b(hnew[i]);
            }
        }

        if (t + 1 < Tt) {
            ull* __restrict__ slab =
                hx + (size_t)(((t + 1) & 1) * 16 + team) * (8 * 256);
            const unsigned want = (unsigned)(t + 1);

            // ---- publish straight from registers (critical path), then
            //      self-inject into next buffer
            if (ex) {
                const ull tg = (ull)want << 48;
                const ull wlo = (ull)hb[0] | ((ull)hb[1] << 16)
                              | ((ull)hb[2] << 32) | tg;
                const ull whi = (ull)hb[3] | tg;
                const int pw = (wg << 8) + ((wv * 16 + lane) << 1);
                __hip_atomic_store(&slab[pw],     wlo,
                                   __ATOMIC_RELAXED, __HIP_MEMORY_SCOPE_AGENT);
                __hip_atomic_store(&slab[pw + 1], whi,
                                   __ATOMIC_RELAXED, __HIP_MEMORY_SCOPE_AGENT);
                hn[sb]      = (short)hb[0];
                hn[sb + 32] = (short)hb[1];
                hn[sb + 64] = (short)hb[2];
                hn[sb + 96] = (short)hb[3];
            }

            // ---- poll remote words; observing load IS the payload
            {
                bool dn[4] = {false, false, npair < 2, npair < 2};
                int  rem = npair << 1;
                while (rem > 0) {
                    ull v[4];
#pragma unroll
                    for (int j = 0; j < 4; ++j) {
                        if (!dn[j])
                            v[j] = __hip_atomic_load(&slab[soff[j >> 1] + (j & 1)],
                                                     __ATOMIC_RELAXED,
                                                     __HIP_MEMORY_SCOPE_AGENT);
                    }
#pragma unroll
                    for (int j = 0; j < 4; ++j) {
                        if (!dn[j] && (unsigned)(v[j] >> 48) == want) {
                            dn[j] = true; --rem;
                            const int base = sbase[j >> 1];
                            if ((j & 1) == 0) {
                                hn[base]      = (short)(v[j] & 0xffffu);
                                hn[base + 32] = (short)((v[j] >> 16) & 0xffffu);
                                hn[base + 64] = (short)((v[j] >> 32) & 0xffffu);
                            } else {
                                hn[base + 96] = (short)(v[j] & 0xffffu);
                            }
                        }
                    }
                }
            }

            // ---- hs output store after poll: hides under the barrier
            if (ex) {
#pragma unroll
                for (int i = 0; i < 4; ++i)
                    Xhs[((size_t)(b0 + i) * Tt + t) * Hh + exrow] = hnew[i];
            }
            __syncthreads();   // hn complete -> becomes hc of step t+1
        } else {
            // last step: just emit hs
            if (ex) {
#pragma unroll
                for (int i = 0; i < 4; ++i)
                    Xhs[((size_t)(b0 + i) * Tt + t) * Hh + exrow] = hnew[i];
            }
        }
    }
}

// ---------------------------------------------------------------- launch
extern "C" void kernel_launch(void* const* d_in, const int* in_sizes, int n_in,
                              void* d_out, int out_size, void* d_ws, size_t ws_size,
                              hipStream_t stream)
{
    (void)in_sizes; (void)n_in; (void)out_size; (void)ws_size;

    const float* obs  = (const float*)d_in[0];  // [64][512][256]
    const float* h0   = (const float*)d_in[1];  // [64][1024]
    const float* Win  = (const float*)d_in[2];  // [1024][256]
    const float* bin  = (const float*)d_in[3];  // [1024]
    const float* Wh   = (const float*)d_in[4];  // [1024][1024]
    const float* bh   = (const float*)d_in[5];  // [1024]
    const float* Wout = (const float*)d_in[6];  // [256][1024]
    const float* bout = (const float*)d_in[7];  // [256]

    float* outs = (float*)d_out;                   // [64][512][256]
    float* hs   = outs + (size_t)Bb * Tt * Oo;     // [64][512][1024] (doubles as X)

    ull* hx = (ull*)d_ws;                          // [2][16][8][256] x 8 B = 512 KB

    // Phase A: X = obs @ W_in^T + b_in + b_h  -> hs region
    gemm_bt_kernel<<<(Bb * Tt / 128) * (Hh / 128), 256, 0, stream>>>(
        obs, Win, bin, bh, hs, Bb * Tt, Hh, Dd);

    // Phase B: sequential recurrence (in-place X -> hs).
    rnn_kernel<<<128, 512, 0, stream>>>(hs, h0, Wh, hx);

    // Phase C: outs = hs @ W_out^T + b_out
    gemm_bt_kernel<<<(Bb * Tt / 128) * (Oo / 128), 256, 0, stream>>>(
        hs, Wout, bout, nullptr, outs, Bb * Tt, Oo, Hh);
}

// Round 5
// 1344.730 us; speedup vs baseline: 1.5255x; 1.2497x over previous
//
#include <hip/hip_runtime.h>
#include <cstddef>

// BasicRNN, Round 8.
// Phase A: X = obs @ W_in^T + b_in + b_h  -> hs region   [split-bf16 MFMA GEMM]
// Phase B: recurrence — EXACT round-6 kernel (passed, 1072us). Untouched.
// Phase C: outs = hs @ W_out^T + b_out                   [plain bf16 MFMA GEMM]
//
// R7 post-mortem: hand vmcnt ledger over compiler-invisible asm VMEM ->
// register corruption/hang. Exchange path frozen at R6 primitives.
// R8 lever: the two fp32 GEMMs (~600us @ 57TF fp32) -> bf16 MFMA (~2.5PF pipe).
//   Phase A uses Markidis split (A=ah+al, B=bh+bl, C = ah*bh + ah*bl + al*bh;
//   dropped al*bl ~ 1e-5) so GEMM error stays ~1e-4 and absmax is unchanged.
//   Phase C plain bf16: error sqrt(1024)*0.004*|W~0.03| ~ 4e-3, negligible.

static constexpr int Bb = 64;
static constexpr int Tt = 512;
static constexpr int Dd = 256;
static constexpr int Hh = 1024;
static constexpr int Oo = 256;

typedef __attribute__((ext_vector_type(8))) short bf16x8;
typedef __attribute__((ext_vector_type(4))) float f32x4;
typedef unsigned long long ull;

static __device__ __forceinline__ unsigned short f2b(float f) {
    unsigned int u = __float_as_uint(f);
    u = (u + 0x7fffu + ((u >> 16) & 1u)) >> 16;
    return (unsigned short)u;
}
static __device__ __forceinline__ float b2f(unsigned short b) {
    return __uint_as_float(((unsigned int)b) << 16);
}
static __device__ __forceinline__ ull pack4(float a, float b, float c, float d) {
    return (ull)f2b(a) | ((ull)f2b(b) << 16) | ((ull)f2b(c) << 32) | ((ull)f2b(d) << 48);
}

// Fragment-major LDS layout for h (row r 0..1023, batch m 0..3) — rnn only.
static __device__ __forceinline__ int hla_base(int r) {
    return ((r >> 5) << 7) + (((r >> 3) & 3) << 3) + (r & 7);
}
static __device__ __forceinline__ int hla_addr(int r, int m) {
    return hla_base(r) + (m << 5);
}

// ---------------------------------------------------------------- MFMA GEMM
// C[m,n] = sum_k A[m,k]*Bt[n,k] + bias1[n] (+bias2[n]).
// Tiles: BM=BN=128, BK=32. 256 threads = 4 waves; wave quadrant 64x64 =
// 4x4 frags of 16x16x32. LDS row stride 40 shorts (80B): every frag read
// (row*80 + (lane>>4)*16) is 16B-aligned; start banks of the 16 rows of a
// frag are evenly spread (20*r mod 32 covers 8 starts x2) -> no extra
// conflict beyond the inherent 2 clk/1KB.
// MFMA layouts (HW-verified in this file's rnn): A-frag lane l =
// A[m=l&15][k=(l>>4)*8+j]; B-frag lane l = B[k=(l>>4)*8+j][n=l&15] which we
// feed with Bt[n][k] at the SAME (l&15 -> n, (l>>4)*8 -> k) pattern;
// D lane l reg i = D[m=(l>>4)*4+i][n=l&15].
// SPLIT=1: Markidis 3-pass split-bf16 (hi+lo per operand).
template <int SPLIT>
__global__ __launch_bounds__(256) void gemm_mfma_bt(const float* __restrict__ A,
                                                    const float* __restrict__ Bt,
                                                    const float* __restrict__ bias1,
                                                    const float* __restrict__ bias2,
                                                    float* __restrict__ C,
                                                    int M, int N, int K)
{
    __shared__ short Ah[128 * 40];
    __shared__ short Bh[128 * 40];
    __shared__ short Al[SPLIT ? 128 * 40 : 8];
    __shared__ short Bl[SPLIT ? 128 * 40 : 8];

    const int tid = threadIdx.x;
    const int nTiles = N >> 7;
    const int mt = blockIdx.x / nTiles;
    const int nt = blockIdx.x - mt * nTiles;
    const int m0 = mt << 7, n0 = nt << 7;

    const int lane = tid & 63;
    const int wv   = tid >> 6;           // 0..3
    const int wr   = (wv >> 1) << 6;     // wave row offset: 0 or 64
    const int wc   = (wv & 1) << 6;      // wave col offset: 0 or 64
    const int fr   = lane & 15;          // row-in-16
    const int fk   = (lane >> 4) << 3;   // k-offset in shorts (0,8,16,24)

    // staging map: thread -> (row 0..127, 16-col half of the 32-wide K-slab)
    const int srow = tid >> 1;
    const int scg  = (tid & 1) << 4;     // 0 or 16

    const float* arow = A  + (size_t)(m0 + srow) * K + scg;
    const float* brow = Bt + (size_t)(n0 + srow) * K + scg;

    f32x4 acc[4][4] = {};

    for (int kt = 0; kt < K; kt += 32) {
        // ---- global prefetch (before the sync, old-kernel pattern)
        float4 av[4], bv[4];
#pragma unroll
        for (int j = 0; j < 4; ++j) {
            av[j] = *(const float4*)(arow + kt + 4 * j);
            bv[j] = *(const float4*)(brow + kt + 4 * j);
        }
        __syncthreads();
        // ---- convert + stage
        {
            short ahl[16], bhl[16], all_[16], bll[16];
#pragma unroll
            for (int j = 0; j < 4; ++j) {
#pragma unroll
                for (int e = 0; e < 4; ++e) {
                    const float fa = (&av[j].x)[e];
                    const float fb = (&bv[j].x)[e];
                    const unsigned short ha = f2b(fa);
                    const unsigned short hb = f2b(fb);
                    ahl[j * 4 + e] = (short)ha;
                    bhl[j * 4 + e] = (short)hb;
                    if constexpr (SPLIT) {
                        all_[j * 4 + e] = (short)f2b(fa - b2f(ha));
                        bll[j * 4 + e] = (short)f2b(fb - b2f(hb));
                    }
                }
            }
            const int sb = srow * 40 + scg;
            *(bf16x8*)&Ah[sb]     = *(bf16x8*)&ahl[0];
            *(bf16x8*)&Ah[sb + 8] = *(bf16x8*)&ahl[8];
            *(bf16x8*)&Bh[sb]     = *(bf16x8*)&bhl[0];
            *(bf16x8*)&Bh[sb + 8] = *(bf16x8*)&bhl[8];
            if constexpr (SPLIT) {
                *(bf16x8*)&Al[sb]     = *(bf16x8*)&all_[0];
                *(bf16x8*)&Al[sb + 8] = *(bf16x8*)&all_[8];
                *(bf16x8*)&Bl[sb]     = *(bf16x8*)&bll[0];
                *(bf16x8*)&Bl[sb + 8] = *(bf16x8*)&bll[8];
            }
        }
        __syncthreads();
        // ---- fragments + MFMA
        bf16x8 ah[4], bh_[4], al[4], bl[4];
#pragma unroll
        for (int i = 0; i < 4; ++i) {
            ah[i]  = *(const bf16x8*)&Ah[(wr + i * 16 + fr) * 40 + fk];
            bh_[i] = *(const bf16x8*)&Bh[(wc + i * 16 + fr) * 40 + fk];
            if constexpr (SPLIT) {
                al[i] = *(const bf16x8*)&Al[(wr + i * 16 + fr) * 40 + fk];
                bl[i] = *(const bf16x8*)&Bl[(wc + i * 16 + fr) * 40 + fk];
            }
        }
#pragma unroll
        for (int mi = 0; mi < 4; ++mi) {
#pragma unroll
            for (int ni = 0; ni < 4; ++ni) {
                acc[mi][ni] = __builtin_amdgcn_mfma_f32_16x16x32_bf16(
                                  ah[mi], bh_[ni], acc[mi][ni], 0, 0, 0);
                if constexpr (SPLIT) {
                    acc[mi][ni] = __builtin_amdgcn_mfma_f32_16x16x32_bf16(
                                      ah[mi], bl[ni], acc[mi][ni], 0, 0, 0);
                    acc[mi][ni] = __builtin_amdgcn_mfma_f32_16x16x32_bf16(
                                      al[mi], bh_[ni], acc[mi][ni], 0, 0, 0);
                }
            }
        }
    }

    // ---- epilogue: bias + store (D: lane l reg i -> m=(l>>4)*4+i, n=l&15)
    float bsv[4];
#pragma unroll
    for (int ni = 0; ni < 4; ++ni) {
        const int col = n0 + wc + ni * 16 + fr;
        bsv[ni] = bias1[col] + (bias2 ? bias2[col] : 0.0f);
    }
#pragma unroll
    for (int mi = 0; mi < 4; ++mi) {
#pragma unroll
        for (int i = 0; i < 4; ++i) {
            const int m = m0 + wr + mi * 16 + ((lane >> 4) << 2) + i;
            float* crow = C + (size_t)m * N;
#pragma unroll
            for (int ni = 0; ni < 4; ++ni) {
                const int col = n0 + wc + ni * 16 + fr;
                crow[col] = acc[mi][ni][i] + bsv[ni];
            }
        }
    }
}

// ---------------------------------------------------------------- recurrence
// EXACT round-6 kernel (passed, 1072us, absmax 0.03125). Do not touch.
// 128 blocks x 512 threads. team = bid&15, wg = bid>>4 (0..7), 128 W_h rows/wg.
// Exchange: word pair for row r of wg j at slab[j*256 + 2*(r-128j) + {0,1}]:
// lo = [hb0 hb1 hb2 | tag16], hi = [hb3 | tag16]; tag = step of the h carried.
// Slab: ull hx[2][16 team][8 wg][256] = 512 KB of d_ws. 2-slab ping-pong;
// 0xAA ws poison -> tag 0xAAAA matches no step.
__global__ __launch_bounds__(512, 2) void rnn_kernel(float* __restrict__ Xhs, // [64][512][1024]
                                                     const float* __restrict__ h0,
                                                     const float* __restrict__ Wh,
                                                     ull* __restrict__ hx)
{
    __shared__ short hlA[2][32 * 128];   // double-buffered fragment-major h (16 KB)

    const int tid  = threadIdx.x;
    const int bid  = blockIdx.x;
    const int team = bid & 15;
    const int wg   = bid >> 4;       // 0..7
    const int r0   = wg << 7;        // 128 W_h rows
    const int b0   = team << 2;      // 4 batch rows

    const int lane = tid & 63;
    const int wv   = tid >> 6;       // 0..7

    // ---- one-time: 128-row W slice -> register-resident bf16 B-fragments
    bf16x8 wfrag[32];
    {
        const float* wrow = Wh + (size_t)(r0 + wv * 16 + (lane & 15)) * Hh + ((lane >> 4) << 3);
#pragma unroll
        for (int s = 0; s < 32; ++s) {
            const float4 lo = *(const float4*)(wrow + s * 32);
            const float4 hi = *(const float4*)(wrow + s * 32 + 4);
            bf16x8 w;
            w[0] = (short)f2b(lo.x); w[1] = (short)f2b(lo.y);
            w[2] = (short)f2b(lo.z); w[3] = (short)f2b(lo.w);
            w[4] = (short)f2b(hi.x); w[5] = (short)f2b(hi.y);
            w[6] = (short)f2b(hi.z); w[7] = (short)f2b(hi.w);
            wfrag[s] = w;
        }
    }

    // ---- one-time: h0 -> hlA[0] (bf16, fragment-major)
#pragma unroll
    for (int it = 0; it < 2; ++it) {
        const int idx = it * 512 + tid;   // 1024 float4 chunks of [4][1024]
        const int b   = idx >> 8;
        const int k0  = (idx & 255) << 2;
        const float4 v = *(const float4*)&h0[(size_t)(b0 + b) * Hh + k0];
        *(ull*)&hlA[0][hla_addr(k0, b)] = pack4(v.x, v.y, v.z, v.w);
    }

    // ---- per-thread poll assignment: row-pairs (7 remote wgs x 128 = 896)
    const int npair = (tid < 384) ? 2 : 1;
    int soff[2], sbase[2];
#pragma unroll
    for (int j = 0; j < 2; ++j) {
        int q = tid + j * 512; if (q >= 896) q = 0;   // dummy, never polled
        const int wr = q >> 7;
        const int rl = q & 127;
        const int wi = wr + ((wr >= wg) ? 1 : 0);      // skip self
        soff[j]  = (wi << 8) + (rl << 1);
        sbase[j] = hla_base((wi << 7) + rl);
    }

    // ---- extraction-lane state: lane<16 owns (batch i=0..3, row exrow)
    const bool ex    = (lane < 16);
    const int  exrow = r0 + wv * 16 + lane;
    const int  sb    = hla_base(exrow);
    float hprev[4] = {0.f, 0.f, 0.f, 0.f};
    if (ex) {
#pragma unroll
        for (int i = 0; i < 4; ++i)
            hprev[i] = h0[(size_t)(b0 + i) * Hh + exrow];
    }
    __syncthreads();

    const int aoff = (lane & 3) * 32 + ((lane >> 4) << 3);   // shorts

    for (int t = 0; t < Tt; ++t) {
        const short* hc = hlA[t & 1];
        short*       hn = hlA[(t + 1) & 1];

        // ---- x(t) load issued first: hides under the MFMA block
        float xr[4] = {0.f, 0.f, 0.f, 0.f};
        if (ex) {
#pragma unroll
            for (int i = 0; i < 4; ++i)
                xr[i] = Xhs[((size_t)(b0 + i) * Tt + t) * Hh + exrow];
        }

        // ---- pre = h(t) @ W^T : 32 MFMAs in 4 independent chains
        f32x4 acc0 = {0.f, 0.f, 0.f, 0.f}, acc1 = acc0, acc2 = acc0, acc3 = acc0;
#pragma unroll
        for (int s = 0; s < 32; s += 4) {
            acc0 = __builtin_amdgcn_mfma_f32_16x16x32_bf16(
                       *(const bf16x8*)(hc + (s + 0) * 128 + aoff), wfrag[s + 0], acc0, 0, 0, 0);
            acc1 = __builtin_amdgcn_mfma_f32_16x16x32_bf16(
                       *(const bf16x8*)(hc + (s + 1) * 128 + aoff), wfrag[s + 1], acc1, 0, 0, 0);
            acc2 = __builtin_amdgcn_mfma_f32_16x16x32_bf16(
                       *(const bf16x8*)(hc + (s + 2) * 128 + aoff), wfrag[s + 2], acc2, 0, 0, 0);
            acc3 = __builtin_amdgcn_mfma_f32_16x16x32_bf16(
                       *(const bf16x8*)(hc + (s + 3) * 128 + aoff), wfrag[s + 3], acc3, 0, 0, 0);
        }
        const f32x4 accs01 = acc0 + acc1;
        const f32x4 accs23 = acc2 + acc3;
        const f32x4 acc    = accs01 + accs23;

        // ---- extract h(t+1) for owned (batch, row)
        float hnew[4] = {0.f, 0.f, 0.f, 0.f};
        unsigned short hb[4] = {0, 0, 0, 0};
        if (ex) {
#pragma unroll
            for (int i = 0; i < 4; ++i) {
                const float pre = acc[i] + xr[i];
                hnew[i]  = 0.5f * fmaxf(pre, 0.0f) + 0.5f * hprev[i];
                hprev[i] = hnew[i];
                hb[i]    = f2b(hnew[i]);
            }
        }

        if (t + 1 < Tt) {
            ull* __restrict__ slab =
                hx + (size_t)(((t + 1) & 1) * 16 + team) * (8 * 256);
            const unsigned want = (unsigned)(t + 1);

            // ---- publish straight from registers (critical path), then
            //      self-inject into next buffer
            if (ex) {
                const ull tg = (ull)want << 48;
                const ull wlo = (ull)hb[0] | ((ull)hb[1] << 16)
                              | ((ull)hb[2] << 32) | tg;
                const ull whi = (ull)hb[3] | tg;
                const int pw = (wg << 8) + ((wv * 16 + lane) << 1);
                __hip_atomic_store(&slab[pw],     wlo,
                                   __ATOMIC_RELAXED, __HIP_MEMORY_SCOPE_AGENT);
                __hip_atomic_store(&slab[pw + 1], whi,
                                   __ATOMIC_RELAXED, __HIP_MEMORY_SCOPE_AGENT);
                hn[sb]      = (short)hb[0];
                hn[sb + 32] = (short)hb[1];
                hn[sb + 64] = (short)hb[2];
                hn[sb + 96] = (short)hb[3];
            }

            // ---- poll remote words; observing load IS the payload
            {
                bool dn[4] = {false, false, npair < 2, npair < 2};
                int  rem = npair << 1;
                while (rem > 0) {
                    ull v[4];
#pragma unroll
                    for (int j = 0; j < 4; ++j) {
                        if (!dn[j])
                            v[j] = __hip_atomic_load(&slab[soff[j >> 1] + (j & 1)],
                                                     __ATOMIC_RELAXED,
                                                     __HIP_MEMORY_SCOPE_AGENT);
                    }
#pragma unroll
                    for (int j = 0; j < 4; ++j) {
                        if (!dn[j] && (unsigned)(v[j] >> 48) == want) {
                            dn[j] = true; --rem;
                            const int base = sbase[j >> 1];
                            if ((j & 1) == 0) {
                                hn[base]      = (short)(v[j] & 0xffffu);
                                hn[base + 32] = (short)((v[j] >> 16) & 0xffffu);
                                hn[base + 64] = (short)((v[j] >> 32) & 0xffffu);
                            } else {
                                hn[base + 96] = (short)(v[j] & 0xffffu);
                            }
                        }
                    }
                }
            }

            // ---- hs output store after poll: hides under the barrier
            if (ex) {
#pragma unroll
                for (int i = 0; i < 4; ++i)
                    Xhs[((size_t)(b0 + i) * Tt + t) * Hh + exrow] = hnew[i];
            }
            __syncthreads();   // hn complete -> becomes hc of step t+1
        } else {
            // last step: just emit hs
            if (ex) {
#pragma unroll
                for (int i = 0; i < 4; ++i)
                    Xhs[((size_t)(b0 + i) * Tt + t) * Hh + exrow] = hnew[i];
            }
        }
    }
}

// ---------------------------------------------------------------- launch
extern "C" void kernel_launch(void* const* d_in, const int* in_sizes, int n_in,
                              void* d_out, int out_size, void* d_ws, size_t ws_size,
                              hipStream_t stream)
{
    (void)in_sizes; (void)n_in; (void)out_size; (void)ws_size;

    const float* obs  = (const float*)d_in[0];  // [64][512][256]
    const float* h0   = (const float*)d_in[1];  // [64][1024]
    const float* Win  = (const float*)d_in[2];  // [1024][256]
    const float* bin  = (const float*)d_in[3];  // [1024]
    const float* Wh   = (const float*)d_in[4];  // [1024][1024]
    const float* bh   = (const float*)d_in[5];  // [1024]
    const float* Wout = (const float*)d_in[6];  // [256][1024]
    const float* bout = (const float*)d_in[7];  // [256]

    float* outs = (float*)d_out;                   // [64][512][256]
    float* hs   = outs + (size_t)Bb * Tt * Oo;     // [64][512][1024] (doubles as X)

    ull* hx = (ull*)d_ws;                          // [2][16][8][256] x 8 B = 512 KB

    // Phase A: X = obs @ W_in^T + b_in + b_h  -> hs region (split-bf16 MFMA)
    gemm_mfma_bt<1><<<(Bb * Tt / 128) * (Hh / 128), 256, 0, stream>>>(
        obs, Win, bin, bh, hs, Bb * Tt, Hh, Dd);

    // Phase B: sequential recurrence (in-place X -> hs). EXACT R6 kernel.
    rnn_kernel<<<128, 512, 0, stream>>>(hs, h0, Wh, hx);

    // Phase C: outs = hs @ W_out^T + b_out (plain bf16 MFMA)
    gemm_mfma_bt<0><<<(Bb * Tt / 128) * (Oo / 128), 256, 0, stream>>>(
        hs, Wout, bout, nullptr, outs, Bb * Tt, Oo, Hh);
}